// Round 13
// baseline (923.041 us; speedup 1.0000x reference)
//
#include <hip/hip_runtime.h>
#include <math.h>

#define DEV __device__ __forceinline__
DEV float frelu(float x) { return x > 0.f ? x : 0.f; }

typedef float f4 __attribute__((ext_vector_type(4)));
typedef short bf16x8 __attribute__((ext_vector_type(8)));
typedef int   i2x  __attribute__((ext_vector_type(2)));

DEV unsigned pack_hi2(float a, float b) {
    return (__float_as_uint(b) & 0xFFFF0000u) | (__float_as_uint(a) >> 16);
}
DEV float hi_part(float a) {
    return __uint_as_float(__float_as_uint(a) & 0xFFFF0000u);
}

// DPP partial-sum (VALU pipe): row_shr chain + row_bcast.
// HW-verified (R11 passing): row_shr:n = lane i reads lane i-n (sum -> lane 63).
#define DPP_ADD(v, ctrl) \
    ((v) + __int_as_float(__builtin_amdgcn_update_dpp(0, __float_as_int(v), (ctrl), 0xf, 0xf, true)))

// DPP row-rotate-right move (VALU pipe): lane i reads lane (i & ~15) | ((i - S) & 15).
// (Same direction as the HW-verified row_shr, with wraparound.)
template<int CTRL>
DEV float dppmov(float v) {
    return __int_as_float(__builtin_amdgcn_update_dpp(0, __float_as_int(v), CTRL, 0xf, 0xf, true));
}

DEV float rdlane(float v, int l) {
    return __int_as_float(__builtin_amdgcn_readlane(__float_as_int(v), l));
}

// ===========================================================================
// Stage 1: conv 3->32 relu -> conv 32->32 relu ; e1 raw ; pool5 -> x1p.
// Zero LDS: conv2 via DPP row-rotations; at step s lane o receives v1 of
// channel (((o&15)-s)&15 | (o&16)) -> weights ordered accordingly.
// ===========================================================================
#define NG1 8
__global__ __launch_bounds__(256) void k_s1(
    const float* __restrict__ x,
    const float* __restrict__ w1, const float* __restrict__ b1,
    const float* __restrict__ w2, const float* __restrict__ b2,
    const float* __restrict__ aW, const float* __restrict__ ab,
    float* __restrict__ x1p, float* __restrict__ e1)
{
    int tid = threadIdx.x;
    int wv = tid >> 6, lane = tid & 63;
    int half = lane >> 5, o = lane & 31;
    int hs = blockIdx.x * 8 + wv * 2 + half;     // 40000 half-slots

    float W1c0 = w1[o], W1c1 = w1[32 + o], W1c2 = w1[64 + o], B1 = b1[o];
    // rotation-ordered conv2 weights: step s delivers v1 of channel
    // iA = ((o&15)-s)&15 | (o&16)  (own row-of-16), iB = iA^16 (other row).
    float W2A[16], W2B[16];
#pragma unroll
    for (int s = 0; s < 16; ++s) {
        int iA = ((((o & 15) + 16 - s) & 15) | (o & 16));
        W2A[s] = w2[iA * 32 + o];
        W2B[s] = w2[(iA ^ 16) * 32 + o];
    }
    float B2 = b2[o];

#pragma unroll 1
    for (int i = 0; i < NG1; ++i) {
        int g = hs * NG1 + i;                    // 0..319999
        int b = g / 5000, r = g % 5000, h = r / 100, pw = r % 100;
        float AWo = aW[h * 32 + o];
        const float* xrow = x + (size_t)((b * 50 + h) * 500) * 3;
        float vmax = 0.f;
#pragma unroll 1
        for (int j = 0; j < 5; ++j) {
            int w = pw * 5 + j;
            float x0 = xrow[w * 3 + 0], x1v = xrow[w * 3 + 1], x2v = xrow[w * 3 + 2];
            float v1 = frelu(fmaf(x0, W1c0, fmaf(x1v, W1c1, fmaf(x2v, W1c2, B1))));
            float v1x = __shfl_xor(v1, 16, 64);
            float aA = fmaf(v1, W2A[0], B2);
            float aB = v1x * W2B[0];
#define S1ROT(s) \
            aA = fmaf(dppmov<0x120 + s>(v1),  W2A[s], aA); \
            aB = fmaf(dppmov<0x120 + s>(v1x), W2B[s], aB);
            S1ROT(1) S1ROT(2) S1ROT(3) S1ROT(4) S1ROT(5)
            S1ROT(6) S1ROT(7) S1ROT(8) S1ROT(9) S1ROT(10)
            S1ROT(11) S1ROT(12) S1ROT(13) S1ROT(14) S1ROT(15)
#undef S1ROT
            float t = frelu(aA + aB);
            vmax = fmaxf(vmax, t);
            float ep = t * AWo;
            ep = DPP_ADD(ep, 0x111);             // row_shr:1
            ep = DPP_ADD(ep, 0x112);             // row_shr:2
            ep = DPP_ADD(ep, 0x114);             // row_shr:4
            ep = DPP_ADD(ep, 0x118);             // row_shr:8
            ep = DPP_ADD(ep, 0x142);             // row_bcast15
            if (o == 31) e1[(b * 50 + h) * 500 + w] = ep + ab[h * 500 + w];
        }
        x1p[(size_t)g * 32 + o] = vmax;
    }
}

// ===========================================================================
// Stage 2: conv 32->64 relu -> conv 64->64 relu ; e2 raw ; pool5 -> x2p.
// Zero LDS: conv2 via DPP rotations over 4 row-group variants.
// ===========================================================================
#define NG2 8
__global__ __launch_bounds__(256) void k_s2(
    const float* __restrict__ x1p,
    const float* __restrict__ w1, const float* __restrict__ b1,
    const float* __restrict__ w2, const float* __restrict__ b2,
    const float* __restrict__ aW, const float* __restrict__ ab,
    float* __restrict__ x2p, float* __restrict__ e2)
{
    int tid = threadIdx.x;
    int wv = tid >> 6, o = tid & 63;
    int slot = blockIdx.x * 4 + wv;              // 8000 slots

    float W1[32];
#pragma unroll
    for (int i = 0; i < 32; ++i) W1[i] = w1[i * 64 + o];
    // W2r[g][s]: variant g, step s sources v1 of channel
    // ((o&15)-s)&15 | ((o&48)^(g<<4)).
    float W2r[4][16];
#pragma unroll
    for (int gg = 0; gg < 4; ++gg)
#pragma unroll
        for (int s = 0; s < 16; ++s) {
            int idx = ((((o & 15) + 16 - s) & 15) | ((o & 48) ^ (gg << 4)));
            W2r[gg][s] = w2[idx * 64 + o];
        }
    float B1 = b1[o], B2 = b2[o];

#pragma unroll 1
    for (int i = 0; i < NG2; ++i) {
        int g = slot * NG2 + i;                  // 0..63999
        int b = g / 1000, r = g % 1000, h = r / 20, pw = r % 20;
        float AWo = aW[h * 64 + o];
        float vmax = 0.f;
#pragma unroll 1
        for (int j = 0; j < 5; ++j) {
            int w = pw * 5 + j;
            const float* in = x1p + (size_t)((b * 50 + h) * 100 + w) * 32;
            float a1 = B1;
#pragma unroll
            for (int q = 0; q < 32; q += 4) {
                float4 a4 = *(const float4*)&in[q];
                a1 = fmaf(a4.x, W1[q + 0], a1);
                a1 = fmaf(a4.y, W1[q + 1], a1);
                a1 = fmaf(a4.z, W1[q + 2], a1);
                a1 = fmaf(a4.w, W1[q + 3], a1);
            }
            float v1r = frelu(a1);
            float v16 = __shfl_xor(v1r, 16, 64);
            float v32 = __shfl_xor(v1r, 32, 64);
            float v48 = __shfl_xor(v1r, 48, 64);
            float c0 = fmaf(v1r, W2r[0][0], B2);
            float c1 = v16 * W2r[1][0];
            float c2 = v32 * W2r[2][0];
            float c3 = v48 * W2r[3][0];
#define S2ROT(s) \
            c0 = fmaf(dppmov<0x120 + s>(v1r), W2r[0][s], c0); \
            c1 = fmaf(dppmov<0x120 + s>(v16), W2r[1][s], c1); \
            c2 = fmaf(dppmov<0x120 + s>(v32), W2r[2][s], c2); \
            c3 = fmaf(dppmov<0x120 + s>(v48), W2r[3][s], c3);
            S2ROT(1) S2ROT(2) S2ROT(3) S2ROT(4) S2ROT(5)
            S2ROT(6) S2ROT(7) S2ROT(8) S2ROT(9) S2ROT(10)
            S2ROT(11) S2ROT(12) S2ROT(13) S2ROT(14) S2ROT(15)
#undef S2ROT
            float t = frelu((c0 + c1) + (c2 + c3));
            vmax = fmaxf(vmax, t);
            float ep = t * AWo;
            ep = DPP_ADD(ep, 0x111);
            ep = DPP_ADD(ep, 0x112);
            ep = DPP_ADD(ep, 0x114);
            ep = DPP_ADD(ep, 0x118);
            ep = DPP_ADD(ep, 0x142);             // row_bcast15
            ep = DPP_ADD(ep, 0x143);             // row_bcast31
            if (o == 63) e2[(b * 50 + h) * 100 + w] = ep + ab[h * 100 + w];
        }
        x2p[(size_t)g * 64 + o] = vmax;
    }
}

// ===========================================================================
// Stage 3: conv 64->128 relu -> conv 128->128 relu ; e3 raw ; pool4 -> x3p.
// Own-half conv2 via DPP rotations; cross-half via LDS b128 broadcasts.
// ===========================================================================
#define NG3 8
__global__ __launch_bounds__(256) void k_s3(
    const float* __restrict__ x2p,
    const float* __restrict__ w1, const float* __restrict__ b1,
    const float* __restrict__ w2, const float* __restrict__ b2,
    const float* __restrict__ aW, const float* __restrict__ ab,
    float* __restrict__ x3p, float* __restrict__ e3)
{
    __shared__ float v1s[2][128];
    __shared__ float epart[2][2];
    int tid = threadIdx.x;
    int wv = tid >> 6, lane = tid & 63;
    int slot = wv >> 1, oh = wv & 1;
    int o = oh * 64 + lane;
    int gs = blockIdx.x * 2 + slot;              // 2000 slots

    float W1[64];
#pragma unroll
    for (int i = 0; i < 64; ++i) W1[i] = w1[i * 128 + o];
    // own-half rotated weights: channel oh*64 + (((lane&15)-s)&15 | ((lane&48)^(g<<4)))
    float W2o[4][16];
#pragma unroll
    for (int gg = 0; gg < 4; ++gg)
#pragma unroll
        for (int s = 0; s < 16; ++s) {
            int idx = oh * 64 + ((((lane & 15) + 16 - s) & 15) | ((lane & 48) ^ (gg << 4)));
            W2o[gg][s] = w2[idx * 128 + o];
        }
    // cross-half weights (channels (oh^1)*64 + i)
    float W2x[64];
#pragma unroll
    for (int i = 0; i < 64; ++i) W2x[i] = w2[((oh ^ 1) * 64 + i) * 128 + o];
    float B1 = b1[o], B2 = b2[o];
    int xbase = (oh ^ 1) * 64;

#pragma unroll 1
    for (int i = 0; i < NG3; ++i) {
        int g = gs * NG3 + i;                    // 0..15999
        int b = g / 250, r = g % 250, h = r / 5, pw = r % 5;
        float AWo = aW[h * 128 + o];
        float vmax = 0.f;
#pragma unroll 1
        for (int j = 0; j < 4; ++j) {
            int w = pw * 4 + j;
            const float* in = x2p + (size_t)((b * 50 + h) * 20 + w) * 64;
            float a1a = B1, a1b = 0.f;
#pragma unroll
            for (int q = 0; q < 64; q += 8) {
                float4 a4 = *(const float4*)&in[q];
                float4 b4 = *(const float4*)&in[q + 4];
                a1a = fmaf(a4.x, W1[q + 0], a1a);
                a1b = fmaf(a4.y, W1[q + 1], a1b);
                a1a = fmaf(a4.z, W1[q + 2], a1a);
                a1b = fmaf(a4.w, W1[q + 3], a1b);
                a1a = fmaf(b4.x, W1[q + 4], a1a);
                a1b = fmaf(b4.y, W1[q + 5], a1b);
                a1a = fmaf(b4.z, W1[q + 6], a1a);
                a1b = fmaf(b4.w, W1[q + 7], a1b);
            }
            float myv = frelu(a1a + a1b);
            v1s[slot][o] = myv;                  // publish for other wave
            __syncthreads();
            // own half via DPP rotations
            float v16 = __shfl_xor(myv, 16, 64);
            float v32 = __shfl_xor(myv, 32, 64);
            float v48 = __shfl_xor(myv, 48, 64);
            float c0 = fmaf(myv, W2o[0][0], B2);
            float c1 = v16 * W2o[1][0];
            float c2 = v32 * W2o[2][0];
            float c3 = v48 * W2o[3][0];
#define S3ROT(s) \
            c0 = fmaf(dppmov<0x120 + s>(myv), W2o[0][s], c0); \
            c1 = fmaf(dppmov<0x120 + s>(v16), W2o[1][s], c1); \
            c2 = fmaf(dppmov<0x120 + s>(v32), W2o[2][s], c2); \
            c3 = fmaf(dppmov<0x120 + s>(v48), W2o[3][s], c3);
            S3ROT(1) S3ROT(2) S3ROT(3) S3ROT(4) S3ROT(5)
            S3ROT(6) S3ROT(7) S3ROT(8) S3ROT(9) S3ROT(10)
            S3ROT(11) S3ROT(12) S3ROT(13) S3ROT(14) S3ROT(15)
#undef S3ROT
            // cross half via LDS broadcast reads
            float d0 = 0.f, d1 = 0.f, d2 = 0.f, d3 = 0.f;
#pragma unroll
            for (int q = 0; q < 64; q += 4) {
                float4 v4 = *(const float4*)&v1s[slot][xbase + q];
                d0 = fmaf(v4.x, W2x[q + 0], d0);
                d1 = fmaf(v4.y, W2x[q + 1], d1);
                d2 = fmaf(v4.z, W2x[q + 2], d2);
                d3 = fmaf(v4.w, W2x[q + 3], d3);
            }
            float t = frelu(((c0 + c1) + (c2 + c3)) + ((d0 + d1) + (d2 + d3)));
            vmax = fmaxf(vmax, t);
            float ep = t * AWo;
            ep = DPP_ADD(ep, 0x111);
            ep = DPP_ADD(ep, 0x112);
            ep = DPP_ADD(ep, 0x114);
            ep = DPP_ADD(ep, 0x118);
            ep = DPP_ADD(ep, 0x142);
            ep = DPP_ADD(ep, 0x143);
            if (lane == 63) epart[slot][oh] = ep;
            __syncthreads();
            if (lane == 63 && oh == 0)
                e3[(b * 50 + h) * 20 + w] = epart[slot][0] + epart[slot][1] + ab[h * 20 + w];
        }
        x3p[(size_t)g * 128 + o] = vmax;
    }
}

// ===========================================================================
// Top-k (k=10, value desc, tie -> lower index) + feature recompute.
// ===========================================================================
__global__ __launch_bounds__(64) void k_t1(
    const float* __restrict__ e1, const float* __restrict__ x,
    const float* __restrict__ w1, const float* __restrict__ b1,
    const float* __restrict__ w2, const float* __restrict__ b2,
    float* __restrict__ z)
{
    int blk = blockIdx.x; int b = blk / 50; int h = blk % 50;
    int lane = threadIdx.x;
    const float* er = e1 + (b * 50 + h) * 500;
    float ev0 = er[lane];
    float ev1 = er[64 + lane];
    float ev2 = er[128 + lane];
    float ev3 = er[192 + lane];
    float ev4 = er[256 + lane];
    float ev5 = er[320 + lane];
    float ev6 = er[384 + lane];
    float ev7 = (448 + lane < 500) ? er[448 + lane] : -1e30f;

    for (int k = 0; k < 10; ++k) {
        float bv = ev0; int bi = lane;
        if (ev1 > bv) { bv = ev1; bi = 64 + lane; }
        if (ev2 > bv) { bv = ev2; bi = 128 + lane; }
        if (ev3 > bv) { bv = ev3; bi = 192 + lane; }
        if (ev4 > bv) { bv = ev4; bi = 256 + lane; }
        if (ev5 > bv) { bv = ev5; bi = 320 + lane; }
        if (ev6 > bv) { bv = ev6; bi = 384 + lane; }
        if (ev7 > bv) { bv = ev7; bi = 448 + lane; }
#pragma unroll
        for (int d = 1; d < 64; d <<= 1) {
            float ov = __shfl_xor(bv, d, 64); int oi = __shfl_xor(bi, d, 64);
            if (ov > bv || (ov == bv && oi < bi)) { bv = ov; bi = oi; }
        }
        bool me = (bi & 63) == lane; int cs = bi >> 6;
        if (me && cs == 0) ev0 = -1e30f;
        if (me && cs == 1) ev1 = -1e30f;
        if (me && cs == 2) ev2 = -1e30f;
        if (me && cs == 3) ev3 = -1e30f;
        if (me && cs == 4) ev4 = -1e30f;
        if (me && cs == 5) ev5 = -1e30f;
        if (me && cs == 6) ev6 = -1e30f;
        if (me && cs == 7) ev7 = -1e30f;

        const float* px = x + (size_t)((b * 50 + h) * 500 + bi) * 3;
        float x0 = px[0], x1v = px[1], x2v = px[2];
        int o = lane & 31;
        float v1 = frelu(fmaf(x0, w1[o], fmaf(x1v, w1[32 + o], fmaf(x2v, w1[64 + o], b1[o]))));
        float v2 = b2[o];
#pragma unroll 8
        for (int i = 0; i < 32; ++i) v2 = fmaf(rdlane(v1, i), w2[i * 32 + o], v2);
        if (lane < 32) z[(size_t)b * 112000 + h * 320 + k * 32 + o] = frelu(v2);
    }
}

__global__ __launch_bounds__(64) void k_t2(
    const float* __restrict__ e2, const float* __restrict__ x1p,
    const float* __restrict__ w1, const float* __restrict__ b1,
    const float* __restrict__ w2, const float* __restrict__ b2,
    float* __restrict__ z)
{
    int blk = blockIdx.x; int b = blk / 50; int h = blk % 50;
    int lane = threadIdx.x;
    const float* er = e2 + (b * 50 + h) * 100;
    float ev0 = er[lane];
    float ev1 = (64 + lane < 100) ? er[64 + lane] : -1e30f;

    for (int k = 0; k < 10; ++k) {
        float bv = ev0; int bi = lane;
        if (ev1 > bv) { bv = ev1; bi = 64 + lane; }
#pragma unroll
        for (int d = 1; d < 64; d <<= 1) {
            float ov = __shfl_xor(bv, d, 64); int oi = __shfl_xor(bi, d, 64);
            if (ov > bv || (ov == bv && oi < bi)) { bv = ov; bi = oi; }
        }
        bool me = (bi & 63) == lane; int cs = bi >> 6;
        if (me && cs == 0) ev0 = -1e30f;
        if (me && cs == 1) ev1 = -1e30f;

        const float* in = x1p + (size_t)((b * 50 + h) * 100 + bi) * 32;
        float v1p0 = b1[lane], v1p1 = 0.f;
#pragma unroll 8
        for (int i = 0; i < 32; i += 2) {
            v1p0 = fmaf(in[i], w1[i * 64 + lane], v1p0);
            v1p1 = fmaf(in[i + 1], w1[(i + 1) * 64 + lane], v1p1);
        }
        float v1 = frelu(v1p0 + v1p1);
        float v2p0 = b2[lane], v2p1 = 0.f;
#pragma unroll 8
        for (int i = 0; i < 64; i += 2) {
            v2p0 = fmaf(rdlane(v1, i), w2[i * 64 + lane], v2p0);
            v2p1 = fmaf(rdlane(v1, i + 1), w2[(i + 1) * 64 + lane], v2p1);
        }
        z[(size_t)b * 112000 + 16000 + h * 640 + k * 64 + lane] = frelu(v2p0 + v2p1);
    }
}

__global__ __launch_bounds__(64) void k_t3(
    const float* __restrict__ e3, const float* __restrict__ x2p,
    const float* __restrict__ w1, const float* __restrict__ b1,
    const float* __restrict__ w2, const float* __restrict__ b2,
    float* __restrict__ z)
{
    int blk = blockIdx.x; int b = blk / 50; int h = blk % 50;
    int lane = threadIdx.x;
    const float* er = e3 + (b * 50 + h) * 20;
    float ev0 = (lane < 20) ? er[lane] : -1e30f;

    for (int k = 0; k < 10; ++k) {
        float bv = ev0; int bi = lane;
#pragma unroll
        for (int d = 1; d < 64; d <<= 1) {
            float ov = __shfl_xor(bv, d, 64); int oi = __shfl_xor(bi, d, 64);
            if (ov > bv || (ov == bv && oi < bi)) { bv = ov; bi = oi; }
        }
        if (bi == lane) ev0 = -1e30f;
        const float* in = x2p + (size_t)((b * 50 + h) * 20 + bi) * 64;
        float v1a0 = b1[lane], v1a1 = 0.f, v1b0 = b1[lane + 64], v1b1 = 0.f;
#pragma unroll 8
        for (int i = 0; i < 64; i += 2) {
            float a0 = in[i], a1 = in[i + 1];
            v1a0 = fmaf(a0, w1[i * 128 + lane], v1a0);
            v1b0 = fmaf(a0, w1[i * 128 + lane + 64], v1b0);
            v1a1 = fmaf(a1, w1[(i + 1) * 128 + lane], v1a1);
            v1b1 = fmaf(a1, w1[(i + 1) * 128 + lane + 64], v1b1);
        }
        float v1a = frelu(v1a0 + v1a1), v1b = frelu(v1b0 + v1b1);
        float v2a0 = b2[lane], v2a1 = 0.f, v2b0 = b2[lane + 64], v2b1 = 0.f;
#pragma unroll 8
        for (int i = 0; i < 64; i += 2) {
            float s0 = rdlane(v1a, i), s1 = rdlane(v1a, i + 1);
            v2a0 = fmaf(s0, w2[i * 128 + lane], v2a0);
            v2b0 = fmaf(s0, w2[i * 128 + lane + 64], v2b0);
            v2a1 = fmaf(s1, w2[(i + 1) * 128 + lane], v2a1);
            v2b1 = fmaf(s1, w2[(i + 1) * 128 + lane + 64], v2b1);
        }
#pragma unroll 8
        for (int i = 0; i < 64; i += 2) {
            float s0 = rdlane(v1b, i), s1 = rdlane(v1b, i + 1);
            v2a0 = fmaf(s0, w2[(i + 64) * 128 + lane], v2a0);
            v2b0 = fmaf(s0, w2[(i + 64) * 128 + lane + 64], v2b0);
            v2a1 = fmaf(s1, w2[(i + 65) * 128 + lane], v2a1);
            v2b1 = fmaf(s1, w2[(i + 65) * 128 + lane + 64], v2b1);
        }
        size_t base = (size_t)b * 112000 + 48000 + h * 1280 + k * 128;
        z[base + lane] = frelu(v2a0 + v2a1);
        z[base + lane + 64] = frelu(v2b0 + v2b1);
    }
}

// ===========================================================================
// k_zt: transpose z[m][f] (f<112000) -> zT[f][m]
// ===========================================================================
__global__ __launch_bounds__(256) void k_zt(const float* __restrict__ z, float* __restrict__ zT)
{
    __shared__ float t[64][65];
    int f0 = blockIdx.x * 64;                // 1750 blocks
    int tid = threadIdx.x;
    int fl = tid & 63, q = tid >> 6;
#pragma unroll
    for (int rr = 0; rr < 16; ++rr) {
        int m = q * 16 + rr;
        t[m][fl] = z[(size_t)m * 112000 + f0 + fl];
    }
    __syncthreads();
    int m2 = tid & 63;
#pragma unroll
    for (int rr = 0; rr < 16; ++rr) {
        int fl2 = q * 16 + rr;
        zT[(size_t)(f0 + fl2) * 64 + m2] = t[m2][fl2];
    }
}

// ===========================================================================
// k_xf: x3p (B,H,5,128) -> zT rows 112000 + c*250 + h*5 + pw, layout [f][m]
// ===========================================================================
__global__ __launch_bounds__(256) void k_xf(const float* __restrict__ x3p, float* __restrict__ zT)
{
    __shared__ float t[64][129];
    int blk = blockIdx.x;                    // 250
    int h = blk / 5, pw = blk % 5;
    int tid = threadIdx.x;
    for (int idx = tid; idx < 64 * 128; idx += 256) {
        int m = idx >> 7, c = idx & 127;
        t[m][c] = x3p[(size_t)((m * 50 + h) * 5 + pw) * 128 + c];
    }
    __syncthreads();
    for (int idx = tid; idx < 64 * 128; idx += 256) {
        int c = idx >> 6, m = idx & 63;
        zT[(size_t)(112000 + c * 250 + h * 5 + pw) * 64 + m] = t[m][c];
    }
}

// ===========================================================================
// fc1 GEMM — bf16-split MFMA (16x16x32) (unchanged from R10, verified).
// ===========================================================================
__global__ __launch_bounds__(256, 3) void k_gemm1(
    const float* __restrict__ AT, const float* __restrict__ W,
    float* __restrict__ part)
{
    __shared__ char smem[24576];
    const int t = threadIdx.x;
    const int lane = t & 63;
    const int wv = t >> 6;
    const int n0 = blockIdx.x << 7;
    const int kc = blockIdx.y;

    const int nw = t & 127, kqi = t >> 7;
    const int ma = t & 63,  kqa = t >> 6;

    int wadrW[4];
#pragma unroll
    for (int q = 0; q < 4; ++q)
        wadrW[q] = nw * 64 + (((kqi * 2 + (q >> 1)) ^ (nw & 3)) << 4) + ((q & 1) << 3);
    int wadrA[2];
#pragma unroll
    for (int q = 0; q < 2; ++q)
        wadrA[q] = 16384 + ma * 64 + ((kqa ^ (ma & 3)) << 4) + (q << 3);

    const int c = lane & 15, hi = lane >> 4;
    int rW[2], rA[4];
#pragma unroll
    for (int i = 0; i < 2; ++i) {
        int nl = (2 * wv + i) * 16 + c;
        rW[i] = nl * 64 + ((hi ^ (c & 3)) << 4);
    }
#pragma unroll
    for (int mf = 0; mf < 4; ++mf) {
        int ml = mf * 16 + c;
        rA[mf] = 16384 + ml * 64 + ((hi ^ (c & 3)) << 4);
    }

    f4 acc[2][4];
#pragma unroll
    for (int i = 0; i < 2; ++i)
#pragma unroll
        for (int mf = 0; mf < 4; ++mf) acc[i][mf] = (f4)0.f;

    const float* Wp = W + ((size_t)kc * 1152 + kqi * 16) * 1024 + (n0 + nw);
    const float* Ap = AT + ((size_t)kc * 1152 + kqa * 8) * 64 + ma;

    float gw[16], ga[8];
#pragma unroll
    for (int j = 0; j < 16; ++j) gw[j] = Wp[(size_t)j * 1024];
#pragma unroll
    for (int j = 0; j < 8; ++j) ga[j] = Ap[j * 64];
    Wp += 32768; Ap += 2048;

#pragma unroll 1
    for (int cc = 0; cc < 36; ++cc) {
        i2x whv[4], wlv[4], ahv[2], alv[2];
#pragma unroll
        for (int q = 0; q < 4; ++q) {
            float x0 = gw[q * 4 + 0], x1 = gw[q * 4 + 1];
            float x2 = gw[q * 4 + 2], x3 = gw[q * 4 + 3];
            whv[q].x = pack_hi2(x0, x1); whv[q].y = pack_hi2(x2, x3);
            float l0 = x0 - hi_part(x0), l1 = x1 - hi_part(x1);
            float l2 = x2 - hi_part(x2), l3 = x3 - hi_part(x3);
            wlv[q].x = pack_hi2(l0, l1); wlv[q].y = pack_hi2(l2, l3);
        }
#pragma unroll
        for (int q = 0; q < 2; ++q) {
            float x0 = ga[q * 4 + 0], x1 = ga[q * 4 + 1];
            float x2 = ga[q * 4 + 2], x3 = ga[q * 4 + 3];
            ahv[q].x = pack_hi2(x0, x1); ahv[q].y = pack_hi2(x2, x3);
            float l0 = x0 - hi_part(x0), l1 = x1 - hi_part(x1);
            float l2 = x2 - hi_part(x2), l3 = x3 - hi_part(x3);
            alv[q].x = pack_hi2(l0, l1); alv[q].y = pack_hi2(l2, l3);
        }
        __syncthreads();
#pragma unroll
        for (int q = 0; q < 4; ++q) {
            *(i2x*)(smem + wadrW[q]) = whv[q];
            *(i2x*)(smem + wadrW[q] + 8192) = wlv[q];
        }
#pragma unroll
        for (int q = 0; q < 2; ++q) {
            *(i2x*)(smem + wadrA[q]) = ahv[q];
            *(i2x*)(smem + wadrA[q] + 4096) = alv[q];
        }
        if (cc < 35) {
#pragma unroll
            for (int j = 0; j < 16; ++j) gw[j] = Wp[(size_t)j * 1024];
#pragma unroll
            for (int j = 0; j < 8; ++j) ga[j] = Ap[j * 64];
            Wp += 32768; Ap += 2048;
        }
        __syncthreads();

        bf16x8 fwh[2], fwl[2], fah[4], fal[4];
#pragma unroll
        for (int i = 0; i < 2; ++i) {
            fwh[i] = *(const bf16x8*)(smem + rW[i]);
            fwl[i] = *(const bf16x8*)(smem + rW[i] + 8192);
        }
#pragma unroll
        for (int mf = 0; mf < 4; ++mf) {
            fah[mf] = *(const bf16x8*)(smem + rA[mf]);
            fal[mf] = *(const bf16x8*)(smem + rA[mf] + 4096);
        }
#pragma unroll
        for (int i = 0; i < 2; ++i)
#pragma unroll
            for (int mf = 0; mf < 4; ++mf) {
                acc[i][mf] = __builtin_amdgcn_mfma_f32_16x16x32_bf16(fwh[i], fah[mf], acc[i][mf], 0, 0, 0);
                acc[i][mf] = __builtin_amdgcn_mfma_f32_16x16x32_bf16(fwh[i], fal[mf], acc[i][mf], 0, 0, 0);
                acc[i][mf] = __builtin_amdgcn_mfma_f32_16x16x32_bf16(fwl[i], fah[mf], acc[i][mf], 0, 0, 0);
            }
    }

    float* pb = part + ((size_t)kc * 1024 + n0) * 64;
#pragma unroll
    for (int i = 0; i < 2; ++i) {
        int nf = 2 * wv + i;
#pragma unroll
        for (int mf = 0; mf < 4; ++mf) {
#pragma unroll
            for (int q = 0; q < 4; ++q) {
                int n = nf * 16 + hi * 4 + q;
                int m = mf * 16 + c;
                pb[(size_t)n * 64 + m] = acc[i][mf][q];
            }
        }
    }
}

// ===========================================================================
// Generic skinny GEMM (fc2): AT[k][64] uniform (s_load), W[k][n] coalesced.
// ===========================================================================
__global__ __launch_bounds__(256) void k_gemm(
    const float* __restrict__ AT, const float* __restrict__ W,
    float* __restrict__ part, int K, int N, int KC)
{
    int n = blockIdx.x * 256 + threadIdx.x;
    int kc = blockIdx.y;
    int k0 = kc * KC;
    int k1 = k0 + KC; if (k1 > K) k1 = K;
    float acc[64];
#pragma unroll
    for (int m = 0; m < 64; ++m) acc[m] = 0.f;
#pragma unroll 2
    for (int k = k0; k < k1; ++k) {
        float wv = W[(size_t)k * N + n];
        const float4* Ak4 = (const float4*)(AT + (size_t)k * 64);
#pragma unroll
        for (int mq = 0; mq < 16; ++mq) {
            float4 a = Ak4[mq];
            acc[4 * mq + 0] = fmaf(a.x, wv, acc[4 * mq + 0]);
            acc[4 * mq + 1] = fmaf(a.y, wv, acc[4 * mq + 1]);
            acc[4 * mq + 2] = fmaf(a.z, wv, acc[4 * mq + 2]);
            acc[4 * mq + 3] = fmaf(a.w, wv, acc[4 * mq + 3]);
        }
    }
    float4* p4 = (float4*)(part + ((size_t)kc * N + n) * 64);
#pragma unroll
    for (int mq = 0; mq < 16; ++mq)
        p4[mq] = make_float4(acc[4 * mq], acc[4 * mq + 1], acc[4 * mq + 2], acc[4 * mq + 3]);
}

// ===========================================================================
// fc1 reduce: part[kc][n][m] (kc=0..124) -> pp[s][n][m] (s=0..4, 25 each)
// ===========================================================================
__global__ __launch_bounds__(256) void k_redA(
    const float* __restrict__ part, float* __restrict__ pp)
{
    int id = blockIdx.x * 256 + threadIdx.x;  // 81920
    int r = id & 16383; int s = id >> 14;     // s in [0,5)
    const f4* p = (const f4*)part;
    f4 v = (f4)0.f;
#pragma unroll 5
    for (int cidx = s * 25; cidx < s * 25 + 25; ++cidx)
        v += p[(size_t)cidx * 16384 + r];
    ((f4*)pp)[(size_t)s * 16384 + r] = v;
}

// pp[s][n][m] -> h1T[n][m] (+bias, relu).
__global__ __launch_bounds__(256) void k_redB(
    const float* __restrict__ pp, const float* __restrict__ bias,
    float* __restrict__ h1T)
{
    int id = blockIdx.x * 256 + threadIdx.x;  // 16384
    int mq = id & 15, n = id >> 4;
    const f4* p = (const f4*)pp;
    f4 s = (f4)0.f;
#pragma unroll
    for (int cidx = 0; cidx < 5; ++cidx) s += p[(size_t)cidx * 16384 + id];
    float bv = bias[n];
    s += bv;
    s.x = frelu(s.x); s.y = frelu(s.y); s.z = frelu(s.z); s.w = frelu(s.w);
    *(f4*)(h1T + (size_t)n * 64 + mq * 4) = s;
}

// Reduce fc2 partials; write M-MAJOR out[m][n].
__global__ __launch_bounds__(256) void k_red(
    const float* __restrict__ part, const float* __restrict__ bias,
    float* __restrict__ outM, int N, int C)
{
    int id = blockIdx.x * 256 + threadIdx.x;  // N*16
    int mq = id & 15, n = id >> 4;
    f4 s = (f4)0.f;
    for (int cidx = 0; cidx < C; ++cidx)
        s += *(const f4*)(part + ((size_t)cidx * N + n) * 64 + mq * 4);
    float bv = bias[n];
    s += bv;
    outM[(size_t)(mq * 4 + 0) * N + n] = s.x;
    outM[(size_t)(mq * 4 + 1) * N + n] = s.y;
    outM[(size_t)(mq * 4 + 2) * N + n] = s.z;
    outM[(size_t)(mq * 4 + 3) * N + n] = s.w;
}

// ===========================================================================
// fc3: block = one m row; h2M[m][k] wave-uniform (s_load broadcast).
// ===========================================================================
__global__ __launch_bounds__(192) void k_fc3(
    const float* __restrict__ h2M, const float* __restrict__ w3,
    const float* __restrict__ b3, float* __restrict__ out)
{
    int m = blockIdx.x;                      // 64
    int o = threadIdx.x;                     // 192, active < 150
    int oc = o < 150 ? o : 149;
    const float* hr = h2M + (size_t)m * 1024;
    float s = b3[oc];
#pragma unroll 8
    for (int k = 0; k < 1024; ++k) s = fmaf(hr[k], w3[k * 150 + oc], s);
    if (o < 150) out[m * 150 + o] = s;
}

// ---------------------------------------------------------------------------
extern "C" void kernel_launch(void* const* d_in, const int* in_sizes, int n_in,
                              void* d_out, int out_size, void* d_ws, size_t ws_size,
                              hipStream_t stream) {
    const float* X    = (const float*)d_in[0];
    const float* c1w1 = (const float*)d_in[1];
    const float* c1b1 = (const float*)d_in[2];
    const float* c1w2 = (const float*)d_in[3];
    const float* c1b2 = (const float*)d_in[4];
    const float* a1W  = (const float*)d_in[5];
    const float* a1b  = (const float*)d_in[6];
    const float* c2w1 = (const float*)d_in[7];
    const float* c2b1 = (const float*)d_in[8];
    const float* c2w2 = (const float*)d_in[9];
    const float* c2b2 = (const float*)d_in[10];
    const float* a2W  = (const float*)d_in[11];
    const float* a2b  = (const float*)d_in[12];
    const float* c3w1 = (const float*)d_in[13];
    const float* c3b1 = (const float*)d_in[14];
    const float* c3w2 = (const float*)d_in[15];
    const float* c3b2 = (const float*)d_in[16];
    const float* a3W  = (const float*)d_in[17];
    const float* a3b  = (const float*)d_in[18];
    const float* fc1w = (const float*)d_in[19];
    const float* fc1b = (const float*)d_in[20];
    const float* fc2w = (const float*)d_in[21];
    const float* fc2b = (const float*)d_in[22];
    const float* fc3w = (const float*)d_in[23];
    const float* fc3b = (const float*)d_in[24];

    float* ws  = (float*)d_ws;
    float* x1p = ws;                       // [0, 10.24M)
    float* x2p = ws + 10240000;            // [10.24M, 14.336M)
    float* x3p = ws + 14336000;            // [14.336M, 16.384M)
    float* e1  = ws + 16384000;            // [16.384M, 17.984M)
    float* e2  = ws + 17984000;
    float* e3  = ws + 18304000;
    float* z   = ws + 18368000;            // [18.368M, 25.536M)  dead after k_zt
    float* zT  = ws + 25536000;            // [25.536M, 34.752M)  live through k_gemm1
    float* p1  = ws;                       // 125*65536 = 8.192M floats
    float* pp  = ws + 16384000;            // 81,920 (old e1, dead)
    float* h1T = ws + 16600000;            // 65,536
    float* p2  = ws + 16700000;            // 64*1024*64 = 4.19M (ends 20.9M)
    float* h2M = ws + 21000000;            // 65,536

    k_s1<<<5000, 256, 0, stream>>>(X, c1w1, c1b1, c1w2, c1b2, a1W, a1b, x1p, e1);
    k_t1<<<3200, 64, 0, stream>>>(e1, X, c1w1, c1b1, c1w2, c1b2, z);
    k_s2<<<2000, 256, 0, stream>>>(x1p, c2w1, c2b1, c2w2, c2b2, a2W, a2b, x2p, e2);
    k_t2<<<3200, 64, 0, stream>>>(e2, x1p, c2w1, c2b1, c2w2, c2b2, z);
    k_s3<<<1000, 256, 0, stream>>>(x2p, c3w1, c3b1, c3w2, c3b2, a3W, a3b, x3p, e3);
    k_t3<<<3200, 64, 0, stream>>>(e3, x2p, c3w1, c3b1, c3w2, c3b2, z);
    k_zt<<<1750, 256, 0, stream>>>(z, zT);
    k_xf<<<250, 256, 0, stream>>>(x3p, zT);

    k_gemm1<<<dim3(8, 125), 256, 0, stream>>>(zT, fc1w, p1);
    k_redA<<<320, 256, 0, stream>>>(p1, pp);
    k_redB<<<64, 256, 0, stream>>>(pp, fc1b, h1T);
    k_gemm<<<dim3(4, 64), 256, 0, stream>>>(h1T, fc2w, p2, 1024, 1024, 16);
    k_red<<<64, 256, 0, stream>>>(p2, fc2b, h2M, 1024, 64);
    k_fc3<<<64, 192, 0, stream>>>(h2M, fc3w, fc3b, (float*)d_out);
}

// Round 14
// 839.368 us; speedup vs baseline: 1.0997x; 1.0997x over previous
//
#include <hip/hip_runtime.h>
#include <math.h>

#define DEV __device__ __forceinline__
DEV float frelu(float x) { return x > 0.f ? x : 0.f; }

typedef float f4 __attribute__((ext_vector_type(4)));
typedef short bf16x8 __attribute__((ext_vector_type(8)));
typedef int   i2x  __attribute__((ext_vector_type(2)));

DEV unsigned pack_hi2(float a, float b) {
    return (__float_as_uint(b) & 0xFFFF0000u) | (__float_as_uint(a) >> 16);
}
DEV float hi_part(float a) {
    return __uint_as_float(__float_as_uint(a) & 0xFFFF0000u);
}
DEV bf16x8 pack8(const float* v) {
    union { unsigned u[4]; bf16x8 b; } r;
    r.u[0] = pack_hi2(v[0], v[1]);
    r.u[1] = pack_hi2(v[2], v[3]);
    r.u[2] = pack_hi2(v[4], v[5]);
    r.u[3] = pack_hi2(v[6], v[7]);
    return r.b;
}

// DPP partial-sum (VALU pipe), HW-verified: row_shr:n = lane i reads lane i-n.
#define DPP_ADD(v, ctrl) \
    ((v) + __int_as_float(__builtin_amdgcn_update_dpp(0, __float_as_int(v), (ctrl), 0xf, 0xf, true)))

DEV float rdlane(float v, int l) {
    return __int_as_float(__builtin_amdgcn_readlane(__float_as_int(v), l));
}

// ===========================================================================
// Stage 1 — MFMA form. Block = one (b,h) row (3200 blocks); wave = 125-px
// segment. conv1 per-lane (lane c=px-col, hi*8+j = k-channels); conv2 via
// 16x16x32 bf16 MFMA with 3-way split (h+m+l, 6 products -> err ~2^-24,
// rank-flip safe). Frag layouts replicate R10's verified pattern exactly.
// Pool-5 via two-phase LDS staging (80px/16g then 45px/9g), wave-private.
// ===========================================================================
__global__ __launch_bounds__(256) void k_s1(
    const float* __restrict__ x,
    const float* __restrict__ w1, const float* __restrict__ b1,
    const float* __restrict__ w2, const float* __restrict__ b2,
    const float* __restrict__ aW, const float* __restrict__ ab,
    float* __restrict__ x1p, float* __restrict__ e1)
{
    __shared__ float tl[4][80 * 33];             // 42.2 KB
    int tid = threadIdx.x;
    int seg = tid >> 6, lane = tid & 63;
    int row = blockIdx.x;                        // b*50+h
    int h = row % 50;
    int c = lane & 15, hi = lane >> 4;

    // per-lane conv1 weights for k = hi*8+j
    float W1r0[8], W1r1[8], W1r2[8], B1r[8];
#pragma unroll
    for (int j = 0; j < 8; ++j) {
        int k = hi * 8 + j;
        W1r0[j] = w1[k]; W1r1[j] = w1[32 + k]; W1r2[j] = w1[64 + k]; B1r[j] = b1[k];
    }
    // w2 A-frags (R10 pattern: lane -> out-col = i*16+c, k = hi*8+j), 3-way split
    bf16x8 Wh[2], Wm[2], Wl[2];
#pragma unroll
    for (int i = 0; i < 2; ++i) {
        float vh[8], vm[8], vl[8];
#pragma unroll
        for (int j = 0; j < 8; ++j) {
            float wv = w2[(hi * 8 + j) * 32 + i * 16 + c];
            float hh = hi_part(wv); float r1 = wv - hh;
            float mm = hi_part(r1);
            vh[j] = hh; vm[j] = mm; vl[j] = r1 - mm;
        }
        Wh[i] = pack8(vh); Wm[i] = pack8(vm); Wl[i] = pack8(vl);
    }
    // epilogue tables: out = i*16 + hi*4 + q
    float aWr[2][4], b2r[2][4];
#pragma unroll
    for (int i = 0; i < 2; ++i)
#pragma unroll
        for (int q = 0; q < 4; ++q) {
            int o = i * 16 + hi * 4 + q;
            aWr[i][q] = aW[h * 32 + o];
            b2r[i][q] = b2[o];
        }

    const float* xrow = x + (size_t)row * 1500;
    float* tw = &tl[seg][0];

#define S1_FRAG(fv, slot)                                                     \
    {                                                                          \
        int px = seg * 125 + (fv) * 16 + c;                                    \
        int pxc = px < 500 ? px : 499;                                         \
        float x0 = xrow[pxc * 3], x1v = xrow[pxc * 3 + 1], x2v = xrow[pxc * 3 + 2]; \
        float vh[8], vm[8], vl[8];                                             \
        _Pragma("unroll")                                                      \
        for (int j = 0; j < 8; ++j) {                                          \
            float v = frelu(fmaf(x0, W1r0[j], fmaf(x1v, W1r1[j], fmaf(x2v, W1r2[j], B1r[j])))); \
            float hh = hi_part(v); float r1 = v - hh;                          \
            float mm = hi_part(r1);                                            \
            vh[j] = hh; vm[j] = mm; vl[j] = r1 - mm;                           \
        }                                                                      \
        bf16x8 Bh = pack8(vh), Bm = pack8(vm), Bl = pack8(vl);                 \
        f4 a0 = (f4)0.f, a1 = (f4)0.f;                                         \
        a0 = __builtin_amdgcn_mfma_f32_16x16x32_bf16(Wh[0], Bh, a0, 0, 0, 0);  \
        a0 = __builtin_amdgcn_mfma_f32_16x16x32_bf16(Wh[0], Bm, a0, 0, 0, 0);  \
        a0 = __builtin_amdgcn_mfma_f32_16x16x32_bf16(Wm[0], Bh, a0, 0, 0, 0);  \
        a0 = __builtin_amdgcn_mfma_f32_16x16x32_bf16(Wh[0], Bl, a0, 0, 0, 0);  \
        a0 = __builtin_amdgcn_mfma_f32_16x16x32_bf16(Wl[0], Bh, a0, 0, 0, 0);  \
        a0 = __builtin_amdgcn_mfma_f32_16x16x32_bf16(Wm[0], Bm, a0, 0, 0, 0);  \
        a1 = __builtin_amdgcn_mfma_f32_16x16x32_bf16(Wh[1], Bh, a1, 0, 0, 0);  \
        a1 = __builtin_amdgcn_mfma_f32_16x16x32_bf16(Wh[1], Bm, a1, 0, 0, 0);  \
        a1 = __builtin_amdgcn_mfma_f32_16x16x32_bf16(Wm[1], Bh, a1, 0, 0, 0);  \
        a1 = __builtin_amdgcn_mfma_f32_16x16x32_bf16(Wh[1], Bl, a1, 0, 0, 0);  \
        a1 = __builtin_amdgcn_mfma_f32_16x16x32_bf16(Wl[1], Bh, a1, 0, 0, 0);  \
        a1 = __builtin_amdgcn_mfma_f32_16x16x32_bf16(Wm[1], Bm, a1, 0, 0, 0);  \
        f4 t0, t1;                                                             \
        _Pragma("unroll")                                                      \
        for (int q = 0; q < 4; ++q) {                                          \
            t0[q] = frelu(a0[q] + b2r[0][q]);                                  \
            t1[q] = frelu(a1[q] + b2r[1][q]);                                  \
        }                                                                      \
        *(f4*)&tw[(slot) * 33 + hi * 4] = t0;                                  \
        *(f4*)&tw[(slot) * 33 + 16 + hi * 4] = t1;                             \
        float ep = t0[0] * aWr[0][0] + t0[1] * aWr[0][1]                       \
                 + t0[2] * aWr[0][2] + t0[3] * aWr[0][3]                       \
                 + t1[0] * aWr[1][0] + t1[1] * aWr[1][1]                       \
                 + t1[2] * aWr[1][2] + t1[3] * aWr[1][3];                      \
        ep += __shfl_xor(ep, 16, 64);                                          \
        ep += __shfl_xor(ep, 32, 64);                                          \
        if (lane < 16 && ((fv) < 7 || c < 13))                                 \
            e1[(size_t)row * 500 + px] = ep + ab[h * 500 + px];                \
    }

    // phase A: f = 0..4 -> 80 px -> 16 pool groups
#pragma unroll 1
    for (int f = 0; f < 5; ++f) S1_FRAG(f, f * 16 + c)
#pragma unroll
    for (int it = 0; it < 2; ++it) {
        int u = lane + it * 64;                  // 0..127, 16g x 8qd
        int g = u >> 3, qd = u & 7;
        f4 mx = *(f4*)&tw[(g * 5 + 0) * 33 + qd * 4];
#pragma unroll
        for (int p = 1; p < 5; ++p) {
            f4 v = *(f4*)&tw[(g * 5 + p) * 33 + qd * 4];
            mx[0] = fmaxf(mx[0], v[0]); mx[1] = fmaxf(mx[1], v[1]);
            mx[2] = fmaxf(mx[2], v[2]); mx[3] = fmaxf(mx[3], v[3]);
        }
        *(f4*)(x1p + ((size_t)row * 100 + seg * 25 + g) * 32 + qd * 4) = mx;
    }
    // phase B: f = 5..7 -> 45 px -> 9 pool groups (slots reuse 0..47)
#pragma unroll 1
    for (int f = 5; f < 8; ++f) S1_FRAG(f, (f - 5) * 16 + c)
#pragma unroll
    for (int it = 0; it < 2; ++it) {
        int u = lane + it * 64;
        if (u < 72) {                            // 9g x 8qd
            int g = u >> 3, qd = u & 7;
            f4 mx = *(f4*)&tw[(g * 5 + 0) * 33 + qd * 4];
#pragma unroll
            for (int p = 1; p < 5; ++p) {
                f4 v = *(f4*)&tw[(g * 5 + p) * 33 + qd * 4];
                mx[0] = fmaxf(mx[0], v[0]); mx[1] = fmaxf(mx[1], v[1]);
                mx[2] = fmaxf(mx[2], v[2]); mx[3] = fmaxf(mx[3], v[3]);
            }
            *(f4*)(x1p + ((size_t)row * 100 + seg * 25 + 16 + g) * 32 + qd * 4) = mx;
        }
    }
#undef S1_FRAG
}

// ===========================================================================
// Stage 2 (R11 form): conv 32->64 relu -> conv 64->64 relu ; e2 raw ; pool5
// ===========================================================================
#define NG2 16
__global__ __launch_bounds__(256) void k_s2(
    const float* __restrict__ x1p,
    const float* __restrict__ w1, const float* __restrict__ b1,
    const float* __restrict__ w2, const float* __restrict__ b2,
    const float* __restrict__ aW, const float* __restrict__ ab,
    float* __restrict__ x2p, float* __restrict__ e2)
{
    __shared__ float v1s[4][64];
    int tid = threadIdx.x;
    int wv = tid >> 6, o = tid & 63;
    int slot = blockIdx.x * 4 + wv;              // 4000 slots

    float W1[32];
#pragma unroll
    for (int i = 0; i < 32; ++i) W1[i] = w1[i * 64 + o];
    float W2[64];
#pragma unroll
    for (int i = 0; i < 64; ++i) W2[i] = w2[i * 64 + o];
    float B1 = b1[o], B2 = b2[o];
    float* vs = &v1s[wv][0];

#pragma unroll 1
    for (int i = 0; i < NG2; ++i) {
        int g = slot * NG2 + i;                  // 0..63999
        int b = g / 1000, r = g % 1000, h = r / 20, pw = r % 20;
        float AWo = aW[h * 64 + o];
        float vmax = 0.f;
#pragma unroll 1
        for (int j = 0; j < 5; ++j) {
            int w = pw * 5 + j;
            const float* in = x1p + (size_t)((b * 50 + h) * 100 + w) * 32;
            float a1 = B1;
#pragma unroll
            for (int q = 0; q < 32; q += 4) {
                float4 a4 = *(const float4*)&in[q];
                a1 = fmaf(a4.x, W1[q + 0], a1);
                a1 = fmaf(a4.y, W1[q + 1], a1);
                a1 = fmaf(a4.z, W1[q + 2], a1);
                a1 = fmaf(a4.w, W1[q + 3], a1);
            }
            vs[o] = frelu(a1);
            float a2 = B2;
#pragma unroll
            for (int q = 0; q < 64; q += 4) {
                float4 v4 = *(const float4*)&vs[q];
                a2 = fmaf(v4.x, W2[q + 0], a2);
                a2 = fmaf(v4.y, W2[q + 1], a2);
                a2 = fmaf(v4.z, W2[q + 2], a2);
                a2 = fmaf(v4.w, W2[q + 3], a2);
            }
            float t = frelu(a2);
            vmax = fmaxf(vmax, t);
            float ep = t * AWo;
            ep = DPP_ADD(ep, 0x111);
            ep = DPP_ADD(ep, 0x112);
            ep = DPP_ADD(ep, 0x114);
            ep = DPP_ADD(ep, 0x118);
            ep = DPP_ADD(ep, 0x142);             // row_bcast15
            ep = DPP_ADD(ep, 0x143);             // row_bcast31
            if (o == 63) e2[(b * 50 + h) * 100 + w] = ep + ab[h * 100 + w];
        }
        x2p[(size_t)g * 64 + o] = vmax;
    }
}

// ===========================================================================
// Stage 3 (R11 form): conv 64->128 relu -> conv 128->128 relu ; e3 raw
// ===========================================================================
#define NG3 8
__global__ __launch_bounds__(256) void k_s3(
    const float* __restrict__ x2p,
    const float* __restrict__ w1, const float* __restrict__ b1,
    const float* __restrict__ w2, const float* __restrict__ b2,
    const float* __restrict__ aW, const float* __restrict__ ab,
    float* __restrict__ x3p, float* __restrict__ e3)
{
    __shared__ float v1s[2][128];
    __shared__ float epart[2][2];
    int tid = threadIdx.x;
    int wv = tid >> 6, lane = tid & 63;
    int slot = wv >> 1, oh = wv & 1;
    int o = oh * 64 + lane;
    int gs = blockIdx.x * 2 + slot;              // 2000 slots

    float W1[64];
#pragma unroll
    for (int i = 0; i < 64; ++i) W1[i] = w1[i * 128 + o];
    float W2[128];
#pragma unroll
    for (int i = 0; i < 128; ++i) W2[i] = w2[i * 128 + o];
    float B1 = b1[o], B2 = b2[o];

#pragma unroll 1
    for (int i = 0; i < NG3; ++i) {
        int g = gs * NG3 + i;                    // 0..15999
        int b = g / 250, r = g % 250, h = r / 5, pw = r % 5;
        float AWo = aW[h * 128 + o];
        float vmax = 0.f;
#pragma unroll 1
        for (int j = 0; j < 4; ++j) {
            int w = pw * 4 + j;
            const float* in = x2p + (size_t)((b * 50 + h) * 20 + w) * 64;
            float a1a = B1, a1b = 0.f;
#pragma unroll
            for (int q = 0; q < 64; q += 8) {
                float4 a4 = *(const float4*)&in[q];
                float4 b4 = *(const float4*)&in[q + 4];
                a1a = fmaf(a4.x, W1[q + 0], a1a);
                a1b = fmaf(a4.y, W1[q + 1], a1b);
                a1a = fmaf(a4.z, W1[q + 2], a1a);
                a1b = fmaf(a4.w, W1[q + 3], a1b);
                a1a = fmaf(b4.x, W1[q + 4], a1a);
                a1b = fmaf(b4.y, W1[q + 5], a1b);
                a1a = fmaf(b4.z, W1[q + 6], a1a);
                a1b = fmaf(b4.w, W1[q + 7], a1b);
            }
            v1s[slot][o] = frelu(a1a + a1b);
            __syncthreads();
            float a2a = B2, a2b = 0.f, a2c = 0.f, a2d = 0.f;
#pragma unroll
            for (int q = 0; q < 128; q += 8) {
                float4 a4 = *(const float4*)&v1s[slot][q];
                float4 b4 = *(const float4*)&v1s[slot][q + 4];
                a2a = fmaf(a4.x, W2[q + 0], a2a);
                a2b = fmaf(a4.y, W2[q + 1], a2b);
                a2c = fmaf(a4.z, W2[q + 2], a2c);
                a2d = fmaf(a4.w, W2[q + 3], a2d);
                a2a = fmaf(b4.x, W2[q + 4], a2a);
                a2b = fmaf(b4.y, W2[q + 5], a2b);
                a2c = fmaf(b4.z, W2[q + 6], a2c);
                a2d = fmaf(b4.w, W2[q + 7], a2d);
            }
            float t = frelu((a2a + a2b) + (a2c + a2d));
            vmax = fmaxf(vmax, t);
            float ep = t * AWo;
            ep = DPP_ADD(ep, 0x111);
            ep = DPP_ADD(ep, 0x112);
            ep = DPP_ADD(ep, 0x114);
            ep = DPP_ADD(ep, 0x118);
            ep = DPP_ADD(ep, 0x142);
            ep = DPP_ADD(ep, 0x143);
            if (lane == 63) epart[slot][oh] = ep;
            __syncthreads();
            if (lane == 63 && oh == 0)
                e3[(b * 50 + h) * 20 + w] = epart[slot][0] + epart[slot][1] + ab[h * 20 + w];
        }
        x3p[(size_t)g * 128 + o] = vmax;
    }
}

// ===========================================================================
// Top-k + feature recompute (R11 forms, rdlane gathers).
// ===========================================================================
__global__ __launch_bounds__(64) void k_t1(
    const float* __restrict__ e1, const float* __restrict__ x,
    const float* __restrict__ w1, const float* __restrict__ b1,
    const float* __restrict__ w2, const float* __restrict__ b2,
    float* __restrict__ z)
{
    int blk = blockIdx.x; int b = blk / 50; int h = blk % 50;
    int lane = threadIdx.x;
    const float* er = e1 + (b * 50 + h) * 500;
    float ev0 = er[lane];
    float ev1 = er[64 + lane];
    float ev2 = er[128 + lane];
    float ev3 = er[192 + lane];
    float ev4 = er[256 + lane];
    float ev5 = er[320 + lane];
    float ev6 = er[384 + lane];
    float ev7 = (448 + lane < 500) ? er[448 + lane] : -1e30f;

    for (int k = 0; k < 10; ++k) {
        float bv = ev0; int bi = lane;
        if (ev1 > bv) { bv = ev1; bi = 64 + lane; }
        if (ev2 > bv) { bv = ev2; bi = 128 + lane; }
        if (ev3 > bv) { bv = ev3; bi = 192 + lane; }
        if (ev4 > bv) { bv = ev4; bi = 256 + lane; }
        if (ev5 > bv) { bv = ev5; bi = 320 + lane; }
        if (ev6 > bv) { bv = ev6; bi = 384 + lane; }
        if (ev7 > bv) { bv = ev7; bi = 448 + lane; }
#pragma unroll
        for (int d = 1; d < 64; d <<= 1) {
            float ov = __shfl_xor(bv, d, 64); int oi = __shfl_xor(bi, d, 64);
            if (ov > bv || (ov == bv && oi < bi)) { bv = ov; bi = oi; }
        }
        bool me = (bi & 63) == lane; int cs = bi >> 6;
        if (me && cs == 0) ev0 = -1e30f;
        if (me && cs == 1) ev1 = -1e30f;
        if (me && cs == 2) ev2 = -1e30f;
        if (me && cs == 3) ev3 = -1e30f;
        if (me && cs == 4) ev4 = -1e30f;
        if (me && cs == 5) ev5 = -1e30f;
        if (me && cs == 6) ev6 = -1e30f;
        if (me && cs == 7) ev7 = -1e30f;

        const float* px = x + (size_t)((b * 50 + h) * 500 + bi) * 3;
        float x0 = px[0], x1v = px[1], x2v = px[2];
        int o = lane & 31;
        float v1 = frelu(fmaf(x0, w1[o], fmaf(x1v, w1[32 + o], fmaf(x2v, w1[64 + o], b1[o]))));
        float v2 = b2[o];
#pragma unroll 8
        for (int i = 0; i < 32; ++i) v2 = fmaf(rdlane(v1, i), w2[i * 32 + o], v2);
        if (lane < 32) z[(size_t)b * 112000 + h * 320 + k * 32 + o] = frelu(v2);
    }
}

__global__ __launch_bounds__(64) void k_t2(
    const float* __restrict__ e2, const float* __restrict__ x1p,
    const float* __restrict__ w1, const float* __restrict__ b1,
    const float* __restrict__ w2, const float* __restrict__ b2,
    float* __restrict__ z)
{
    int blk = blockIdx.x; int b = blk / 50; int h = blk % 50;
    int lane = threadIdx.x;
    const float* er = e2 + (b * 50 + h) * 100;
    float ev0 = er[lane];
    float ev1 = (64 + lane < 100) ? er[64 + lane] : -1e30f;

    for (int k = 0; k < 10; ++k) {
        float bv = ev0; int bi = lane;
        if (ev1 > bv) { bv = ev1; bi = 64 + lane; }
#pragma unroll
        for (int d = 1; d < 64; d <<= 1) {
            float ov = __shfl_xor(bv, d, 64); int oi = __shfl_xor(bi, d, 64);
            if (ov > bv || (ov == bv && oi < bi)) { bv = ov; bi = oi; }
        }
        bool me = (bi & 63) == lane; int cs = bi >> 6;
        if (me && cs == 0) ev0 = -1e30f;
        if (me && cs == 1) ev1 = -1e30f;

        const float* in = x1p + (size_t)((b * 50 + h) * 100 + bi) * 32;
        float v1p0 = b1[lane], v1p1 = 0.f;
#pragma unroll 8
        for (int i = 0; i < 32; i += 2) {
            v1p0 = fmaf(in[i], w1[i * 64 + lane], v1p0);
            v1p1 = fmaf(in[i + 1], w1[(i + 1) * 64 + lane], v1p1);
        }
        float v1 = frelu(v1p0 + v1p1);
        float v2p0 = b2[lane], v2p1 = 0.f;
#pragma unroll 8
        for (int i = 0; i < 64; i += 2) {
            v2p0 = fmaf(rdlane(v1, i), w2[i * 64 + lane], v2p0);
            v2p1 = fmaf(rdlane(v1, i + 1), w2[(i + 1) * 64 + lane], v2p1);
        }
        z[(size_t)b * 112000 + 16000 + h * 640 + k * 64 + lane] = frelu(v2p0 + v2p1);
    }
}

__global__ __launch_bounds__(64) void k_t3(
    const float* __restrict__ e3, const float* __restrict__ x2p,
    const float* __restrict__ w1, const float* __restrict__ b1,
    const float* __restrict__ w2, const float* __restrict__ b2,
    float* __restrict__ z)
{
    int blk = blockIdx.x; int b = blk / 50; int h = blk % 50;
    int lane = threadIdx.x;
    const float* er = e3 + (b * 50 + h) * 20;
    float ev0 = (lane < 20) ? er[lane] : -1e30f;

    for (int k = 0; k < 10; ++k) {
        float bv = ev0; int bi = lane;
#pragma unroll
        for (int d = 1; d < 64; d <<= 1) {
            float ov = __shfl_xor(bv, d, 64); int oi = __shfl_xor(bi, d, 64);
            if (ov > bv || (ov == bv && oi < bi)) { bv = ov; bi = oi; }
        }
        if (bi == lane) ev0 = -1e30f;
        const float* in = x2p + (size_t)((b * 50 + h) * 20 + bi) * 64;
        float v1a0 = b1[lane], v1a1 = 0.f, v1b0 = b1[lane + 64], v1b1 = 0.f;
#pragma unroll 8
        for (int i = 0; i < 64; i += 2) {
            float a0 = in[i], a1 = in[i + 1];
            v1a0 = fmaf(a0, w1[i * 128 + lane], v1a0);
            v1b0 = fmaf(a0, w1[i * 128 + lane + 64], v1b0);
            v1a1 = fmaf(a1, w1[(i + 1) * 128 + lane], v1a1);
            v1b1 = fmaf(a1, w1[(i + 1) * 128 + lane + 64], v1b1);
        }
        float v1a = frelu(v1a0 + v1a1), v1b = frelu(v1b0 + v1b1);
        float v2a0 = b2[lane], v2a1 = 0.f, v2b0 = b2[lane + 64], v2b1 = 0.f;
#pragma unroll 8
        for (int i = 0; i < 64; i += 2) {
            float s0 = rdlane(v1a, i), s1 = rdlane(v1a, i + 1);
            v2a0 = fmaf(s0, w2[i * 128 + lane], v2a0);
            v2b0 = fmaf(s0, w2[i * 128 + lane + 64], v2b0);
            v2a1 = fmaf(s1, w2[(i + 1) * 128 + lane], v2a1);
            v2b1 = fmaf(s1, w2[(i + 1) * 128 + lane + 64], v2b1);
        }
#pragma unroll 8
        for (int i = 0; i < 64; i += 2) {
            float s0 = rdlane(v1b, i), s1 = rdlane(v1b, i + 1);
            v2a0 = fmaf(s0, w2[(i + 64) * 128 + lane], v2a0);
            v2b0 = fmaf(s0, w2[(i + 64) * 128 + lane + 64], v2b0);
            v2a1 = fmaf(s1, w2[(i + 65) * 128 + lane], v2a1);
            v2b1 = fmaf(s1, w2[(i + 65) * 128 + lane + 64], v2b1);
        }
        size_t base = (size_t)b * 112000 + 48000 + h * 1280 + k * 128;
        z[base + lane] = frelu(v2a0 + v2a1);
        z[base + lane + 64] = frelu(v2b0 + v2b1);
    }
}

// ===========================================================================
// k_zt: transpose z[m][f] (f<112000) -> zT[f][m]
// ===========================================================================
__global__ __launch_bounds__(256) void k_zt(const float* __restrict__ z, float* __restrict__ zT)
{
    __shared__ float t[64][65];
    int f0 = blockIdx.x * 64;                // 1750 blocks
    int tid = threadIdx.x;
    int fl = tid & 63, q = tid >> 6;
#pragma unroll
    for (int rr = 0; rr < 16; ++rr) {
        int m = q * 16 + rr;
        t[m][fl] = z[(size_t)m * 112000 + f0 + fl];
    }
    __syncthreads();
    int m2 = tid & 63;
#pragma unroll
    for (int rr = 0; rr < 16; ++rr) {
        int fl2 = q * 16 + rr;
        zT[(size_t)(f0 + fl2) * 64 + m2] = t[m2][fl2];
    }
}

// ===========================================================================
// k_xf: x3p (B,H,5,128) -> zT rows 112000 + c*250 + h*5 + pw, layout [f][m]
// ===========================================================================
__global__ __launch_bounds__(256) void k_xf(const float* __restrict__ x3p, float* __restrict__ zT)
{
    __shared__ float t[64][129];
    int blk = blockIdx.x;                    // 250
    int h = blk / 5, pw = blk % 5;
    int tid = threadIdx.x;
    for (int idx = tid; idx < 64 * 128; idx += 256) {
        int m = idx >> 7, c = idx & 127;
        t[m][c] = x3p[(size_t)((m * 50 + h) * 5 + pw) * 128 + c];
    }
    __syncthreads();
    for (int idx = tid; idx < 64 * 128; idx += 256) {
        int c = idx >> 6, m = idx & 63;
        zT[(size_t)(112000 + c * 250 + h * 5 + pw) * 64 + m] = t[m][c];
    }
}

// ===========================================================================
// fc1 GEMM — bf16-split MFMA (R10, verified).
// ===========================================================================
__global__ __launch_bounds__(256, 3) void k_gemm1(
    const float* __restrict__ AT, const float* __restrict__ W,
    float* __restrict__ part)
{
    __shared__ char smem[24576];
    const int t = threadIdx.x;
    const int lane = t & 63;
    const int wv = t >> 6;
    const int n0 = blockIdx.x << 7;
    const int kc = blockIdx.y;

    const int nw = t & 127, kqi = t >> 7;
    const int ma = t & 63,  kqa = t >> 6;

    int wadrW[4];
#pragma unroll
    for (int q = 0; q < 4; ++q)
        wadrW[q] = nw * 64 + (((kqi * 2 + (q >> 1)) ^ (nw & 3)) << 4) + ((q & 1) << 3);
    int wadrA[2];
#pragma unroll
    for (int q = 0; q < 2; ++q)
        wadrA[q] = 16384 + ma * 64 + ((kqa ^ (ma & 3)) << 4) + (q << 3);

    const int c = lane & 15, hi = lane >> 4;
    int rW[2], rA[4];
#pragma unroll
    for (int i = 0; i < 2; ++i) {
        int nl = (2 * wv + i) * 16 + c;
        rW[i] = nl * 64 + ((hi ^ (c & 3)) << 4);
    }
#pragma unroll
    for (int mf = 0; mf < 4; ++mf) {
        int ml = mf * 16 + c;
        rA[mf] = 16384 + ml * 64 + ((hi ^ (c & 3)) << 4);
    }

    f4 acc[2][4];
#pragma unroll
    for (int i = 0; i < 2; ++i)
#pragma unroll
        for (int mf = 0; mf < 4; ++mf) acc[i][mf] = (f4)0.f;

    const float* Wp = W + ((size_t)kc * 1152 + kqi * 16) * 1024 + (n0 + nw);
    const float* Ap = AT + ((size_t)kc * 1152 + kqa * 8) * 64 + ma;

    float gw[16], ga[8];
#pragma unroll
    for (int j = 0; j < 16; ++j) gw[j] = Wp[(size_t)j * 1024];
#pragma unroll
    for (int j = 0; j < 8; ++j) ga[j] = Ap[j * 64];
    Wp += 32768; Ap += 2048;

#pragma unroll 1
    for (int cc = 0; cc < 36; ++cc) {
        i2x whv[4], wlv[4], ahv[2], alv[2];
#pragma unroll
        for (int q = 0; q < 4; ++q) {
            float x0 = gw[q * 4 + 0], x1 = gw[q * 4 + 1];
            float x2 = gw[q * 4 + 2], x3 = gw[q * 4 + 3];
            whv[q].x = pack_hi2(x0, x1); whv[q].y = pack_hi2(x2, x3);
            float l0 = x0 - hi_part(x0), l1 = x1 - hi_part(x1);
            float l2 = x2 - hi_part(x2), l3 = x3 - hi_part(x3);
            wlv[q].x = pack_hi2(l0, l1); wlv[q].y = pack_hi2(l2, l3);
        }
#pragma unroll
        for (int q = 0; q < 2; ++q) {
            float x0 = ga[q * 4 + 0], x1 = ga[q * 4 + 1];
            float x2 = ga[q * 4 + 2], x3 = ga[q * 4 + 3];
            ahv[q].x = pack_hi2(x0, x1); ahv[q].y = pack_hi2(x2, x3);
            float l0 = x0 - hi_part(x0), l1 = x1 - hi_part(x1);
            float l2 = x2 - hi_part(x2), l3 = x3 - hi_part(x3);
            alv[q].x = pack_hi2(l0, l1); alv[q].y = pack_hi2(l2, l3);
        }
        __syncthreads();
#pragma unroll
        for (int q = 0; q < 4; ++q) {
            *(i2x*)(smem + wadrW[q]) = whv[q];
            *(i2x*)(smem + wadrW[q] + 8192) = wlv[q];
        }
#pragma unroll
        for (int q = 0; q < 2; ++q) {
            *(i2x*)(smem + wadrA[q]) = ahv[q];
            *(i2x*)(smem + wadrA[q] + 4096) = alv[q];
        }
        if (cc < 35) {
#pragma unroll
            for (int j = 0; j < 16; ++j) gw[j] = Wp[(size_t)j * 1024];
#pragma unroll
            for (int j = 0; j < 8; ++j) ga[j] = Ap[j * 64];
            Wp += 32768; Ap += 2048;
        }
        __syncthreads();

        bf16x8 fwh[2], fwl[2], fah[4], fal[4];
#pragma unroll
        for (int i = 0; i < 2; ++i) {
            fwh[i] = *(const bf16x8*)(smem + rW[i]);
            fwl[i] = *(const bf16x8*)(smem + rW[i] + 8192);
        }
#pragma unroll
        for (int mf = 0; mf < 4; ++mf) {
            fah[mf] = *(const bf16x8*)(smem + rA[mf]);
            fal[mf] = *(const bf16x8*)(smem + rA[mf] + 4096);
        }
#pragma unroll
        for (int i = 0; i < 2; ++i)
#pragma unroll
            for (int mf = 0; mf < 4; ++mf) {
                acc[i][mf] = __builtin_amdgcn_mfma_f32_16x16x32_bf16(fwh[i], fah[mf], acc[i][mf], 0, 0, 0);
                acc[i][mf] = __builtin_amdgcn_mfma_f32_16x16x32_bf16(fwh[i], fal[mf], acc[i][mf], 0, 0, 0);
                acc[i][mf] = __builtin_amdgcn_mfma_f32_16x16x32_bf16(fwl[i], fah[mf], acc[i][mf], 0, 0, 0);
            }
    }

    float* pb = part + ((size_t)kc * 1024 + n0) * 64;
#pragma unroll
    for (int i = 0; i < 2; ++i) {
        int nf = 2 * wv + i;
#pragma unroll
        for (int mf = 0; mf < 4; ++mf) {
#pragma unroll
            for (int q = 0; q < 4; ++q) {
                int n = nf * 16 + hi * 4 + q;
                int m = mf * 16 + c;
                pb[(size_t)n * 64 + m] = acc[i][mf][q];
            }
        }
    }
}

// ===========================================================================
// Generic skinny GEMM (fc2).
// ===========================================================================
__global__ __launch_bounds__(256) void k_gemm(
    const float* __restrict__ AT, const float* __restrict__ W,
    float* __restrict__ part, int K, int N, int KC)
{
    int n = blockIdx.x * 256 + threadIdx.x;
    int kc = blockIdx.y;
    int k0 = kc * KC;
    int k1 = k0 + KC; if (k1 > K) k1 = K;
    float acc[64];
#pragma unroll
    for (int m = 0; m < 64; ++m) acc[m] = 0.f;
#pragma unroll 2
    for (int k = k0; k < k1; ++k) {
        float wv = W[(size_t)k * N + n];
        const float4* Ak4 = (const float4*)(AT + (size_t)k * 64);
#pragma unroll
        for (int mq = 0; mq < 16; ++mq) {
            float4 a = Ak4[mq];
            acc[4 * mq + 0] = fmaf(a.x, wv, acc[4 * mq + 0]);
            acc[4 * mq + 1] = fmaf(a.y, wv, acc[4 * mq + 1]);
            acc[4 * mq + 2] = fmaf(a.z, wv, acc[4 * mq + 2]);
            acc[4 * mq + 3] = fmaf(a.w, wv, acc[4 * mq + 3]);
        }
    }
    float4* p4 = (float4*)(part + ((size_t)kc * N + n) * 64);
#pragma unroll
    for (int mq = 0; mq < 16; ++mq)
        p4[mq] = make_float4(acc[4 * mq], acc[4 * mq + 1], acc[4 * mq + 2], acc[4 * mq + 3]);
}

// ===========================================================================
// fc1 reduce: part[kc][n][m] (kc=0..124) -> pp[s][n][m] (s=0..4, 25 each)
// ===========================================================================
__global__ __launch_bounds__(256) void k_redA(
    const float* __restrict__ part, float* __restrict__ pp)
{
    int id = blockIdx.x * 256 + threadIdx.x;  // 81920
    int r = id & 16383; int s = id >> 14;     // s in [0,5)
    const f4* p = (const f4*)part;
    f4 v = (f4)0.f;
#pragma unroll 5
    for (int cidx = s * 25; cidx < s * 25 + 25; ++cidx)
        v += p[(size_t)cidx * 16384 + r];
    ((f4*)pp)[(size_t)s * 16384 + r] = v;
}

// pp[s][n][m] -> h1T[n][m] (+bias, relu).
__global__ __launch_bounds__(256) void k_redB(
    const float* __restrict__ pp, const float* __restrict__ bias,
    float* __restrict__ h1T)
{
    int id = blockIdx.x * 256 + threadIdx.x;  // 16384
    int mq = id & 15, n = id >> 4;
    const f4* p = (const f4*)pp;
    f4 s = (f4)0.f;
#pragma unroll
    for (int cidx = 0; cidx < 5; ++cidx) s += p[(size_t)cidx * 16384 + id];
    float bv = bias[n];
    s += bv;
    s.x = frelu(s.x); s.y = frelu(s.y); s.z = frelu(s.z); s.w = frelu(s.w);
    *(f4*)(h1T + (size_t)n * 64 + mq * 4) = s;
}

// Reduce fc2 partials; write M-MAJOR out[m][n].
__global__ __launch_bounds__(256) void k_red(
    const float* __restrict__ part, const float* __restrict__ bias,
    float* __restrict__ outM, int N, int C)
{
    int id = blockIdx.x * 256 + threadIdx.x;  // N*16
    int mq = id & 15, n = id >> 4;
    f4 s = (f4)0.f;
    for (int cidx = 0; cidx < C; ++cidx)
        s += *(const f4*)(part + ((size_t)cidx * N + n) * 64 + mq * 4);
    float bv = bias[n];
    s += bv;
    outM[(size_t)(mq * 4 + 0) * N + n] = s.x;
    outM[(size_t)(mq * 4 + 1) * N + n] = s.y;
    outM[(size_t)(mq * 4 + 2) * N + n] = s.z;
    outM[(size_t)(mq * 4 + 3) * N + n] = s.w;
}

// ===========================================================================
// fc3: block = one m row; h2M[m][k] wave-uniform (s_load broadcast).
// ===========================================================================
__global__ __launch_bounds__(192) void k_fc3(
    const float* __restrict__ h2M, const float* __restrict__ w3,
    const float* __restrict__ b3, float* __restrict__ out)
{
    int m = blockIdx.x;                      // 64
    int o = threadIdx.x;                     // 192, active < 150
    int oc = o < 150 ? o : 149;
    const float* hr = h2M + (size_t)m * 1024;
    float s = b3[oc];
#pragma unroll 8
    for (int k = 0; k < 1024; ++k) s = fmaf(hr[k], w3[k * 150 + oc], s);
    if (o < 150) out[m * 150 + o] = s;
}

// ---------------------------------------------------------------------------
extern "C" void kernel_launch(void* const* d_in, const int* in_sizes, int n_in,
                              void* d_out, int out_size, void* d_ws, size_t ws_size,
                              hipStream_t stream) {
    const float* X    = (const float*)d_in[0];
    const float* c1w1 = (const float*)d_in[1];
    const float* c1b1 = (const float*)d_in[2];
    const float* c1w2 = (const float*)d_in[3];
    const float* c1b2 = (const float*)d_in[4];
    const float* a1W  = (const float*)d_in[5];
    const float* a1b  = (const float*)d_in[6];
    const float* c2w1 = (const float*)d_in[7];
    const float* c2b1 = (const float*)d_in[8];
    const float* c2w2 = (const float*)d_in[9];
    const float* c2b2 = (const float*)d_in[10];
    const float* a2W  = (const float*)d_in[11];
    const float* a2b  = (const float*)d_in[12];
    const float* c3w1 = (const float*)d_in[13];
    const float* c3b1 = (const float*)d_in[14];
    const float* c3w2 = (const float*)d_in[15];
    const float* c3b2 = (const float*)d_in[16];
    const float* a3W  = (const float*)d_in[17];
    const float* a3b  = (const float*)d_in[18];
    const float* fc1w = (const float*)d_in[19];
    const float* fc1b = (const float*)d_in[20];
    const float* fc2w = (const float*)d_in[21];
    const float* fc2b = (const float*)d_in[22];
    const float* fc3w = (const float*)d_in[23];
    const float* fc3b = (const float*)d_in[24];

    float* ws  = (float*)d_ws;
    float* x1p = ws;                       // [0, 10.24M)
    float* x2p = ws + 10240000;            // [10.24M, 14.336M)
    float* x3p = ws + 14336000;            // [14.336M, 16.384M)
    float* e1  = ws + 16384000;            // [16.384M, 17.984M)
    float* e2  = ws + 17984000;
    float* e3  = ws + 18304000;
    float* z   = ws + 18368000;            // [18.368M, 25.536M)  dead after k_zt
    float* zT  = ws + 25536000;            // [25.536M, 34.752M)  live through k_gemm1
    float* p1  = ws;                       // 125*65536 = 8.192M floats
    float* pp  = ws + 16384000;            // 81,920 (old e1, dead)
    float* h1T = ws + 16600000;            // 65,536
    float* p2  = ws + 16700000;            // 64*1024*64 = 4.19M (ends 20.9M)
    float* h2M = ws + 21000000;            // 65,536

    k_s1<<<3200, 256, 0, stream>>>(X, c1w1, c1b1, c1w2, c1b2, a1W, a1b, x1p, e1);
    k_t1<<<3200, 64, 0, stream>>>(e1, X, c1w1, c1b1, c1w2, c1b2, z);
    k_s2<<<1000, 256, 0, stream>>>(x1p, c2w1, c2b1, c2w2, c2b2, a2W, a2b, x2p, e2);
    k_t2<<<3200, 64, 0, stream>>>(e2, x1p, c2w1, c2b1, c2w2, c2b2, z);
    k_s3<<<1000, 256, 0, stream>>>(x2p, c3w1, c3b1, c3w2, c3b2, a3W, a3b, x3p, e3);
    k_t3<<<3200, 64, 0, stream>>>(e3, x2p, c3w1, c3b1, c3w2, c3b2, z);
    k_zt<<<1750, 256, 0, stream>>>(z, zT);
    k_xf<<<250, 256, 0, stream>>>(x3p, zT);

    k_gemm1<<<dim3(8, 125), 256, 0, stream>>>(zT, fc1w, p1);
    k_redA<<<320, 256, 0, stream>>>(p1, pp);
    k_redB<<<64, 256, 0, stream>>>(pp, fc1b, h1T);
    k_gemm<<<dim3(4, 64), 256, 0, stream>>>(h1T, fc2w, p2, 1024, 1024, 16);
    k_red<<<64, 256, 0, stream>>>(p2, fc2b, h2M, 1024, 64);
    k_fc3<<<64, 192, 0, stream>>>(h2M, fc3w, fc3b, (float*)d_out);
}